// Round 16
// baseline (603.308 us; speedup 1.0000x reference)
//
#include <hip/hip_runtime.h>
#include <math.h>

#define N_NODES 50000
#define N_EDGES 800000

typedef __bf16 bf16;
typedef __bf16 bf16x8 __attribute__((ext_vector_type(8)));
typedef float f32x4 __attribute__((ext_vector_type(4)));

__device__ __forceinline__ float bflo(unsigned r) {
  union { unsigned u; float f; } c; c.u = r << 16; return c.f;
}
__device__ __forceinline__ float bfhi(unsigned r) {
  union { unsigned u; float f; } c; c.u = r & 0xffff0000u; return c.f;
}

// packed 2xbf16 dot with f32 accumulate; HW instruction when available
__device__ __forceinline__ float dot2bf(unsigned a, unsigned b, float acc) {
#if defined(__has_builtin)
#if __has_builtin(__builtin_amdgcn_fdot2_f32_bf16)
  typedef __bf16 bf16x2 __attribute__((ext_vector_type(2)));
  union { unsigned u; bf16x2 v; } ca, cb;
  ca.u = a; cb.u = b;
  return __builtin_amdgcn_fdot2_f32_bf16(ca.v, cb.v, acc, false);
#else
  return acc + bflo(a) * bflo(b) + bfhi(a) * bfhi(b);
#endif
#else
  return acc + bflo(a) * bflo(b) + bfhi(a) * bfhi(b);
#endif
}

// async global->LDS, 16B per lane; LDS dest = wave-uniform base + lane*16
__device__ __forceinline__ void gload_lds16(const void* g, void* l) {
  __builtin_amdgcn_global_load_lds(
      (const __attribute__((address_space(1))) void*)g,
      (__attribute__((address_space(3))) void*)l, 16, 0, 0);
}

// ---------------- edge-index width detection (int64 vs int32, device-side) ----
__global__ void k_detect(const int* ei, int* flags) {
  if (threadIdx.x == 0 && blockIdx.x == 0) {
    int is64 = 1;
    for (int i = 0; i < 128; ++i) {
      if (ei[2 * i + 1] != 0) { is64 = 0; break; }
    }
    flags[0] = is64;
  }
}

__device__ __forceinline__ int load_idx(const int* ei, int e, int is64, int which) {
  size_t idx = (size_t)which * N_EDGES + (size_t)e;
  return is64 ? ei[2 * idx] : ei[idx];
}

// ---------------- CSR build ----------------

__global__ void k_zero(int* p, int n) {
  int i = blockIdx.x * blockDim.x + threadIdx.x;
  if (i < n) p[i] = 0;
}

__global__ void k_hist(const int* ei, const int* flags, int* counts) {
  int e = blockIdx.x * blockDim.x + threadIdx.x;
  int is64 = flags[0];
  if (e < N_EDGES) {
    int dst = load_idx(ei, e, is64, 1);
    if (dst >= 0 && dst < N_NODES) atomicAdd(&counts[dst], 1);
  }
}

// Multi-block scan: pass1 local scan per 1024-chunk, pass2 scan chunk sums,
// pass3 add carries.
__global__ void k_scan1(const int* counts, int* row_ptr, int* bsum) {
  __shared__ int buf[1024];
  int t = threadIdx.x;
  int i = blockIdx.x * 1024 + t;
  int v = (i < N_NODES) ? counts[i] : 0;
  buf[t] = v;
  __syncthreads();
  for (int off = 1; off < 1024; off <<= 1) {
    int x = (t >= off) ? buf[t - off] : 0;
    __syncthreads();
    buf[t] += x;
    __syncthreads();
  }
  if (i < N_NODES) row_ptr[i] = buf[t] - v;   // chunk-local exclusive
  if (t == 1023) bsum[blockIdx.x] = buf[1023];
}

__global__ void k_scan2(int* bsum, int* row_ptr) {   // 1 block, 64 threads
  constexpr int NB = (N_NODES + 1023) / 1024;        // 49
  int t = threadIdx.x;
  int v = (t < NB) ? bsum[t] : 0;
  int inc = v;
#pragma unroll
  for (int off = 1; off < 64; off <<= 1) {
    int x = __shfl_up(inc, off, 64);
    if (t >= off) inc += x;
  }
  if (t < NB) bsum[t] = inc - v;                     // exclusive chunk carry
  if (t == 63) row_ptr[N_NODES] = inc;               // grand total
}

__global__ void k_scan3(const int* bsum, int* row_ptr, int* cursor) {
  int i = blockIdx.x * 1024 + threadIdx.x;
  if (i < N_NODES) {
    int r = row_ptr[i] + bsum[blockIdx.x];
    row_ptr[i] = r;
    cursor[i] = r;
  }
}

__global__ void k_scatter(const int* ei, const int* flags, int* cursor,
                          int* csr_src, int* csr_eid) {
  int e = blockIdx.x * blockDim.x + threadIdx.x;
  int is64 = flags[0];
  if (e < N_EDGES) {
    int src = load_idx(ei, e, is64, 0);
    int dst = load_idx(ei, e, is64, 1);
    if (dst >= 0 && dst < N_NODES && src >= 0 && src < N_NODES) {
      int pos = atomicAdd(&cursor[dst], 1);
      if (pos >= 0 && pos < N_EDGES) {
        csr_src[pos] = src;
        csr_eid[pos] = e;
      }
    }
  }
}

// ---------------- ea permute into CSR order (bf16), shared by all 3 layers ----

__global__ void k_eaperm(const float* __restrict__ ea, const int* __restrict__ csr_eid,
                         bf16* __restrict__ ea_bf) {
  int idx = blockIdx.x * blockDim.x + threadIdx.x;   // over N_EDGES*16
  if (idx >= N_EDGES * 16) return;
  int p = idx >> 4, jj = idx & 15;
  int eid = csr_eid[p];
  float2 t = *(const float2*)(ea + (size_t)eid * 32 + 2 * jj);
  union { bf16 b[2]; unsigned u; } c;
  c.b[0] = (bf16)t.x; c.b[1] = (bf16)t.y;
  *(unsigned*)(ea_bf + (size_t)p * 32 + 2 * jj) = c.u;
}

// ---------------- degree sort (hierarchical counting sort, buckets 0..63) ----

#define DBLK 256
#define NDB ((N_NODES + DBLK - 1) / DBLK)   // 196

__global__ void k_dhist(const int* __restrict__ counts, int* __restrict__ btot) {
  __shared__ int lh[64];
  int t = threadIdx.x;
  if (t < 64) lh[t] = 0;
  __syncthreads();
  int n = blockIdx.x * DBLK + t;
  if (n < N_NODES) atomicAdd(&lh[min(counts[n], 63)], 1);
  __syncthreads();
  if (t < 64 && lh[t] > 0) atomicAdd(&btot[t], lh[t]);
}

__global__ void k_dbase(const int* __restrict__ btot, int* __restrict__ dcursor) {
  int t = threadIdx.x;
  int v = btot[t];
  int inc = v;
#pragma unroll
  for (int off = 1; off < 64; off <<= 1) {
    int x = __shfl_up(inc, off, 64);
    if (t >= off) inc += x;
  }
  dcursor[t] = inc - v;
}

__global__ void k_dscatter(const int* __restrict__ counts, int* __restrict__ dcursor,
                           int* __restrict__ node_perm) {
  __shared__ int lh[64];
  __shared__ int lbase[64];
  int t = threadIdx.x;
  if (t < 64) lh[t] = 0;
  __syncthreads();
  int n = blockIdx.x * DBLK + t;
  int b = 0, lrank = 0;
  bool valid = (n < N_NODES);
  if (valid) {
    b = min(counts[n], 63);
    lrank = atomicAdd(&lh[b], 1);     // LDS atomic with return: fast
  }
  __syncthreads();
  if (t < 64) {
    int c = lh[t];
    lbase[t] = (c > 0) ? atomicAdd(&dcursor[t], c) : 0;  // <=64 global atomics/block
  }
  __syncthreads();
  if (valid) node_perm[lbase[b] + lrank] = n;
}

// ---------------- weight prep: Wt[pos][k-swz] = combined^T (bf16), bias[pos] ----
// Feat-position permutation folded here (GEMM epilogue is identity).
// k index XOR-swizzled within each 8-row group (ks = k ^ ((pos&7)<<3)) so the
// GEMM stages Wt LINEARLY via global_load_lds and still gets conflict-free
// ds_read_b128 (rule #21: swizzle SOURCE + READ, keep LDS dest linear).

template <int FI, int FO>
__global__ void k_prep(const float* __restrict__ Wq, const float* __restrict__ bq,
                       const float* __restrict__ Wk, const float* __restrict__ bk,
                       const float* __restrict__ Wv, const float* __restrict__ bv,
                       const float* __restrict__ We,
                       const float* __restrict__ Ws, const float* __restrict__ bs,
                       bf16* __restrict__ Wt, float* __restrict__ bias) {
  constexpr int CPL = FO / 16;
  int n = blockIdx.x;    // 0..NT-1 (combined-column space)
  int k = threadIdx.x;   // 0..FI-1
  int pos;
  if (n < 4 * FO) {
    int sel = n / FO, c = n - sel * FO;
    if (sel == 0) pos = c;
    else if (sel == 3) pos = 3 * FO + c;
    else {
      int g = c / CPL, o = c - g * CPL;
      pos = FO + g * 2 * CPL + (sel == 2 ? CPL : 0) + o;
    }
  } else {
    pos = n;
  }
  int ks = k ^ ((pos & 7) << 3);          // bank-conflict swizzle (see above)
  if (n < 4 * FO) {
    int sel = n / FO, c = n - sel * FO;
    const float* W = sel == 0 ? Wq : sel == 1 ? Wk : sel == 2 ? Wv : Ws;
    Wt[(size_t)pos * FI + ks] = (bf16)W[(size_t)k * FO + c];
    if (k == 0) bias[pos] = (sel == 0 ? bq : sel == 1 ? bk : sel == 2 ? bv : bs)[c];
  } else {
    int j = n - 4 * FO;
    float acc = 0.f;
    for (int c = 0; c < FO; ++c) acc += Wq[(size_t)k * FO + c] * We[(size_t)j * FO + c];
    Wt[(size_t)pos * FI + ks] = (bf16)acc;
    if (k == 0) {
      float b = 0.f;
      for (int c = 0; c < FO; ++c) b += bq[c] * We[(size_t)j * FO + c];
      bias[pos] = b;
    }
  }
}

// ---------------- MFMA node GEMM -> feat (identity layout) ----------------
// R12 verified: async global_load_lds double-buffered Wt staging took the
// GEMM off the critical list. Block = 64 nodes (4 waves x 16); x frags in
// regs (read once); per chunk: prefetch next Wt tile -> 16 ds_read_b128 +
// 16 MFMA -> packed 8B stores -> barrier. Source-swizzled Wt -> conflict-free.

template <int K, int NT, bool AF32>
__global__ __launch_bounds__(256) void k_gemm_mfma(const void* __restrict__ A,
                                                   const bf16* __restrict__ Wt,
                                                   const float* __restrict__ bias,
                                                   bf16* __restrict__ feat) {
  constexpr int NKB = K / 32;
  constexpr int NCH = (NT + 63) / 64;
  constexpr int CHB = 64 * K * 2;           // full-chunk bytes (16KB @ K=128)
  __shared__ char wbuf[2 * CHB];
  int t = threadIdx.x;
  int lane = t & 63;
  int w = t >> 6;
  int half = lane & 15;
  int quad = lane >> 4;
  int m0 = blockIdx.x * 64 + w * 16;        // wave's 16-node strip
  bool act = (m0 < N_NODES);                // uniform per wave (N%16==0)

  // x fragments in regs, read ONCE (R9 property; R10 showed re-read costs)
  bf16x8 afr[NKB];
  {
    int row = act ? (m0 + half) : (N_NODES - 16 + half);
#pragma unroll
    for (int kb = 0; kb < NKB; ++kb) {
      size_t aoff = (size_t)row * K + kb * 32 + quad * 8;
      if constexpr (AF32) {
        const float* Af = (const float*)A;
        f32x4 lo = *(const f32x4*)(Af + aoff);
        f32x4 hi = *(const f32x4*)(Af + aoff + 4);
#pragma unroll
        for (int j = 0; j < 4; ++j) { afr[kb][j] = (bf16)lo[j]; afr[kb][4 + j] = (bf16)hi[j]; }
      } else {
        afr[kb] = *(const bf16x8*)((const bf16*)A + aoff);
      }
    }
  }

  // async stage of Wt chunk ch into buffer b (linear LDS; source pre-swizzled)
  auto stage = [&](int ch, int b) {
    int cols = NT - ch * 64; if (cols > 64) cols = 64;
    int nb = cols * K * 2;                          // multiple of 4096
    const char* gsrc = (const char*)Wt + (size_t)ch * 64 * K * 2;
    char* lbase = wbuf + b * CHB;
    for (int off = w * 1024; off < nb; off += 4096) // wave-uniform iteration
      gload_lds16(gsrc + off + lane * 16, lbase + off);
  };

  stage(0, 0);
  __syncthreads();                                  // drains vmcnt (guide m97)

  for (int ch = 0; ch < NCH; ++ch) {
    if (ch + 1 < NCH) stage(ch + 1, (ch + 1) & 1);  // prefetch BEFORE compute
    const char* lb = wbuf + (ch & 1) * CHB;
    int c0 = ch * 64;
    f32x4 acc[4] = {};
#pragma unroll
    for (int f = 0; f < 4; ++f) {
      int cb = c0 + f * 16;
      if (cb < NT) {
        int lc = f * 16 + half;                     // local col in chunk
#pragma unroll
        for (int kb = 0; kb < NKB; ++kb) {
          int lin = kb * 64 + quad * 16;
          int swz = lin ^ ((lc & 7) << 4);          // matches k_prep swizzle
          bf16x8 b = *(const bf16x8*)(lb + lc * (K * 2) + swz);
          acc[f] = __builtin_amdgcn_mfma_f32_16x16x32_bf16(b, afr[kb], acc[f], 0, 0, 0);
        }
      }
    }
    if (act) {
#pragma unroll
      for (int f = 0; f < 4; ++f) {
        int cb = c0 + f * 16;
        if (cb < NT) {
          int fcol = cb + quad * 4;                 // 4 consecutive features
          f32x4 bv = *(const f32x4*)(bias + fcol);
          union { bf16 b[4]; uint2 u; } pk;
#pragma unroll
          for (int r = 0; r < 4; ++r) pk.b[r] = (bf16)(acc[f][r] + bv[r]);
          *(uint2*)(feat + (size_t)(m0 + half) * NT + fcol) = pk.u;   // 8B store
        }
      }
    }
    __syncthreads();                                // next chunk staged + safe swap
  }
}

// ---------------- edge attention: one 16-LANE GROUP per dst node ----------------
// R12 PMC: HBM 42%, VALU 33%, nothing saturated -> ~50% memory duty cycle
// (loads and updates strictly alternated). R13: 2-STAGE SOFTWARE PIPELINE --
// issue batch i+1's csr_src/kv/ea loads BEFORE batch i's updates, so gather
// latency hides under softmax VALU (G15/T14). Register arrays statically
// indexed via unrolled macros (rule #20); flip flag is iteration-uniform.

template <int FO, bool FINAL, bool PERM>
__global__ __launch_bounds__(256) void k_edge(const bf16* __restrict__ feat,
                                              const float* __restrict__ ea,
                                              const bf16* __restrict__ ea_bf,
                                              const int* __restrict__ row_ptr,
                                              const int* __restrict__ csr_src,
                                              const int* __restrict__ csr_eid,
                                              const int* __restrict__ node_perm,
                                              const float* __restrict__ We,
                                              bf16* __restrict__ h_out,
                                              const float* __restrict__ Wc,
                                              const float* __restrict__ bc,
                                              float* __restrict__ out) {
  constexpr int FTOT = 4 * FO + 32;
  constexpr int CPL = FO / 16;   // dims per lane within 16-lane group
  constexpr int NU = CPL / 2;    // uints holding the k (resp. v) slice
  int lane16 = threadIdx.x & 15;
  int gid = blockIdx.x * 16 + (threadIdx.x >> 4);
  // heavy nodes first (perm is ascending by degree) -> no straggler tail
  int node = node_perm[N_NODES - 1 - gid];
  int cbase = CPL * lane16;
  const bf16* fq = feat + (size_t)node * FTOT;

  unsigned qr[NU];   // q packed bf16x2
  {
    const unsigned* qp = (const unsigned*)(fq + cbase);
    if constexpr (NU == 4) { uint4 t = *(const uint4*)qp; qr[0]=t.x; qr[1]=t.y; qr[2]=t.z; qr[3]=t.w; }
    else if constexpr (NU == 2) { uint2 t = *(const uint2*)qp; qr[0]=t.x; qr[1]=t.y; }
    else { qr[0] = *qp; }
  }
  float qe0, qe1;
  { unsigned r = *(const unsigned*)(fq + 4 * FO + 2 * lane16); qe0 = bflo(r); qe1 = bfhi(r); }

  float m = -INFINITY, ssum = 0.f, wacc0 = 0.f, wacc1 = 0.f;
  float vacc[CPL];
#pragma unroll
  for (int i = 0; i < CPL; ++i) vacc[i] = 0.f;

  int start = row_ptr[node], end = row_ptr[node + 1];
  const float scaleA = 1.0f / sqrtf((float)FO);

  auto loadkv = [&](int src, unsigned* kv) {
    const unsigned* base = (const unsigned*)(feat + (size_t)src * FTOT + FO) + CPL * lane16;
    if constexpr (CPL == 8) {
      uint4 a = *(const uint4*)base; uint4 b = *(const uint4*)(base + 4);
      kv[0]=a.x; kv[1]=a.y; kv[2]=a.z; kv[3]=a.w; kv[4]=b.x; kv[5]=b.y; kv[6]=b.z; kv[7]=b.w;
    } else if constexpr (CPL == 4) {
      uint4 a = *(const uint4*)base;
      kv[0]=a.x; kv[1]=a.y; kv[2]=a.z; kv[3]=a.w;
    } else {
      uint2 a = *(const uint2*)base;
      kv[0]=a.x; kv[1]=a.y;
    }
  };

  auto loadea = [&](int p, float& e0, float& e1) {
    if constexpr (PERM) {
      unsigned r = *(const unsigned*)(ea_bf + (size_t)p * 32 + 2 * lane16);
      e0 = bflo(r); e1 = bfhi(r);
    } else {
      int eid = csr_eid[p];
      float2 t = *(const float2*)(ea + (size_t)eid * 32 + 2 * lane16);
      e0 = t.x; e1 = t.y;
    }
  };

  auto update = [&](const unsigned* kv, float e0, float e1) {
    float part = qe0 * e0 + qe1 * e1;
#pragma unroll
    for (int u = 0; u < NU; ++u) part = dot2bf(kv[u], qr[u], part);
#pragma unroll
    for (int off = 1; off < 16; off <<= 1) part += __shfl_xor(part, off, 64);
    float alpha = part * scaleA;
    float mnew = fmaxf(m, alpha);
    float sc = __expf(m - mnew);   // exp(-inf)=0 on first edge
    float w = __expf(alpha - mnew);
    ssum = ssum * sc + w;
#pragma unroll
    for (int u = 0; u < NU; ++u) {
      float a = bflo(kv[NU + u]), b = bfhi(kv[NU + u]);
      vacc[2*u]   = vacc[2*u]   * sc + w * a;
      vacc[2*u+1] = vacc[2*u+1] * sc + w * b;
    }
    wacc0 = wacc0 * sc + w * e0;
    wacc1 = wacc1 * sc + w * e1;
    m = mnew;
  };

// load batch of up to 4 edges at position PB (count NB>=1) into KV/E0/E1;
// inactive slots load slot-0's edge (valid address, result unused)
#define LOADB(KV, E0, E1, PB, NBC)                                         \
  do {                                                                     \
    int sx_[4];                                                            \
    _Pragma("unroll") for (int u_ = 0; u_ < 4; ++u_) {                     \
      int pp_ = (PB) + (u_ < (NBC) ? u_ : 0);                              \
      sx_[u_] = csr_src[pp_];                                              \
    }                                                                      \
    _Pragma("unroll") for (int u_ = 0; u_ < 4; ++u_) loadkv(sx_[u_], KV[u_]); \
    _Pragma("unroll") for (int u_ = 0; u_ < 4; ++u_) {                     \
      int pp_ = (PB) + (u_ < (NBC) ? u_ : 0);                              \
      loadea(pp_, E0[u_], E1[u_]);                                         \
    }                                                                      \
  } while (0)

#define UPDB(KV, E0, E1, NBC)                                              \
  do {                                                                     \
    _Pragma("unroll") for (int u_ = 0; u_ < 4; ++u_)                       \
      if (u_ < (NBC)) update(KV[u_], E0[u_], E1[u_]);                      \
  } while (0)

  {
    unsigned kvA[4][8], kvB[4][8];
    float eA0[4], eA1[4], eB0[4], eB1[4];
    int n_cur = end - start; if (n_cur > 4) n_cur = 4;
    if (n_cur > 0) LOADB(kvA, eA0, eA1, start, n_cur);
    int pn = start + n_cur;
    int flip = 0;
    while (n_cur > 0) {
      int n_nxt = end - pn; if (n_nxt > 4) n_nxt = 4;
      if (flip == 0) {
        if (n_nxt > 0) LOADB(kvB, eB0, eB1, pn, n_nxt);   // loads in flight...
        UPDB(kvA, eA0, eA1, n_cur);                        // ...under these updates
      } else {
        if (n_nxt > 0) LOADB(kvA, eA0, eA1, pn, n_nxt);
        UPDB(kvB, eB0, eB1, n_cur);
      }
      pn += n_nxt; n_cur = n_nxt; flip ^= 1;
    }
  }
#undef LOADB
#undef UPDB

  float inv = (ssum > 0.f) ? 1.0f / ssum : 0.f;
  float agg[CPL];
#pragma unroll
  for (int i = 0; i < CPL; ++i) agg[i] = vacc[i];
  // fold edge-attr contribution: agg[c] += sum_j wacc[j] * We[j][c]
#pragma unroll
  for (int jh = 0; jh < 16; ++jh) {
    float w0 = __shfl(wacc0, jh, 16);
    float w1 = __shfl(wacc1, jh, 16);
    const float* r0 = We + (size_t)(2 * jh) * FO + cbase;
    const float* r1 = We + (size_t)(2 * jh + 1) * FO + cbase;
#pragma unroll
    for (int i = 0; i < CPL; ++i) agg[i] += w0 * r0[i] + w1 * r1[i];
  }
  float hv[CPL];
#pragma unroll
  for (int i = 0; i < CPL; ++i) {
    float s = (float)fq[3 * FO + cbase + i];
    hv[i] = fmaxf(agg[i] * inv + s, 0.f);
  }
  if constexpr (!FINAL) {
    unsigned o[NU];
#pragma unroll
    for (int u = 0; u < NU; ++u) {
      union { bf16 b[2]; unsigned u32; } c;
      c.b[0] = (bf16)hv[2*u]; c.b[1] = (bf16)hv[2*u+1];
      o[u] = c.u32;
    }
    unsigned* dst = (unsigned*)(h_out + (size_t)node * FO + cbase);
    if constexpr (NU == 4) { uint4 t; t.x=o[0]; t.y=o[1]; t.z=o[2]; t.w=o[3]; *(uint4*)dst = t; }
    else if constexpr (NU == 2) { uint2 t; t.x=o[0]; t.y=o[1]; *(uint2*)dst = t; }
    else { *dst = o[0]; }
  } else {
    float part2 = 0.f;
#pragma unroll
    for (int i = 0; i < CPL; ++i) part2 += hv[i] * Wc[cbase + i];
#pragma unroll
    for (int off = 1; off < 16; off <<= 1) part2 += __shfl_xor(part2, off, 64);
    if (lane16 == 0) out[node] = part2 + bc[0];   // f32 output
  }
}

// ---------------- launch ----------------

extern "C" void kernel_launch(void* const* d_in, const int* in_sizes, int n_in,
                              void* d_out, int out_size, void* d_ws, size_t ws_size,
                              hipStream_t stream) {
  (void)in_sizes; (void)n_in; (void)out_size;
  const float* x = (const float*)d_in[0];
  const int* ei = (const int*)d_in[1];
  const float* ea = (const float*)d_in[2];
  const float *Wq1 = (const float*)d_in[3], *bq1 = (const float*)d_in[4];
  const float *Wk1 = (const float*)d_in[5], *bk1 = (const float*)d_in[6];
  const float *Wv1 = (const float*)d_in[7], *bv1 = (const float*)d_in[8];
  const float *We1 = (const float*)d_in[9];
  const float *Ws1 = (const float*)d_in[10], *bs1 = (const float*)d_in[11];
  const float *Wq2 = (const float*)d_in[12], *bq2 = (const float*)d_in[13];
  const float *Wk2 = (const float*)d_in[14], *bk2 = (const float*)d_in[15];
  const float *Wv2 = (const float*)d_in[16], *bv2 = (const float*)d_in[17];
  const float *We2 = (const float*)d_in[18];
  const float *Ws2 = (const float*)d_in[19], *bs2 = (const float*)d_in[20];
  const float *Wq3 = (const float*)d_in[21], *bq3 = (const float*)d_in[22];
  const float *Wk3 = (const float*)d_in[23], *bk3 = (const float*)d_in[24];
  const float *Wv3 = (const float*)d_in[25], *bv3 = (const float*)d_in[26];
  const float *We3 = (const float*)d_in[27];
  const float *Ws3 = (const float*)d_in[28], *bs3 = (const float*)d_in[29];
  const float *Wc = (const float*)d_in[30], *bc = (const float*)d_in[31];

  char* ws = (char*)d_ws;
  size_t off = 0;
  auto alloc = [&](size_t bytes) -> void* {
    void* p = ws + off;
    off = (off + bytes + 255) & ~(size_t)255;
    return p;
  };
  bf16* h        = (bf16*)alloc((size_t)N_NODES * 128 * 2);
  int* counts    = (int*)alloc((N_NODES + 1) * 4);
  int* row_ptr   = (int*)alloc((N_NODES + 1) * 4);
  int* cursor    = (int*)alloc((N_NODES + 1) * 4);
  int* csr_src   = (int*)alloc((size_t)N_EDGES * 4);
  int* csr_eid   = (int*)alloc((size_t)N_EDGES * 4);
  int* flags     = (int*)alloc(256);
  bf16* Wt       = (bf16*)alloc(544 * 128 * 2);
  float* bias    = (float*)alloc(544 * 4);
  bf16* feat     = (bf16*)alloc((size_t)N_NODES * 544 * 2);
  int* bsum      = (int*)alloc(64 * 4);
  int* dcount    = (int*)alloc(64 * 4);     // bucket totals
  int* dcursor   = (int*)alloc(64 * 4);     // bucket cursors (bases)
  int* node_perm = (int*)alloc((size_t)N_NODES * 4);
  bf16* ea_bf    = (bf16*)alloc((size_t)N_EDGES * 32 * 2);   // +51.2 MB
  // fall back to un-permuted path if workspace can't hold ea_bf (~126 MB total)
  bool use_perm = (ws_size == 0) || (off <= ws_size);

  constexpr int NB = (N_NODES + 1023) / 1024;   // 49 scan chunks
  constexpr int GB64 = (N_NODES + 63) / 64;     // 782 gemm blocks (64 nodes each)

  // index-width detection + CSR build (shared by all 3 layers)
  k_detect<<<1, 1, 0, stream>>>(ei, flags);
  k_zero<<<(N_NODES + 256) / 256, 256, 0, stream>>>(counts, N_NODES + 1);
  k_zero<<<1, 64, 0, stream>>>(dcount, 64);
  k_hist<<<(N_EDGES + 255) / 256, 256, 0, stream>>>(ei, flags, counts);
  k_scan1<<<NB, 1024, 0, stream>>>(counts, row_ptr, bsum);
  k_scan2<<<1, 64, 0, stream>>>(bsum, row_ptr);
  k_scan3<<<NB, 1024, 0, stream>>>(bsum, row_ptr, cursor);
  // degree sort (hierarchical: LDS hist + per-block bucket reservation)
  k_dhist<<<NDB, DBLK, 0, stream>>>(counts, dcount);
  k_dbase<<<1, 64, 0, stream>>>(dcount, dcursor);
  k_dscatter<<<NDB, DBLK, 0, stream>>>(counts, dcursor, node_perm);
  k_scatter<<<(N_EDGES + 255) / 256, 256, 0, stream>>>(ei, flags, cursor, csr_src, csr_eid);
  if (use_perm) {
    k_eaperm<<<(N_EDGES * 16 + 255) / 256, 256, 0, stream>>>(ea, csr_eid, ea_bf);
  }

  // Layer 1: FI=128, FO=128, NT=544
  k_prep<128, 128><<<544, 128, 0, stream>>>(Wq1, bq1, Wk1, bk1, Wv1, bv1, We1, Ws1, bs1,
                                            Wt, bias);
  k_gemm_mfma<128, 544, true><<<GB64, 256, 0, stream>>>(x, Wt, bias, feat);
  if (use_perm)
    k_edge<128, false, true><<<N_NODES / 16, 256, 0, stream>>>(feat, ea, ea_bf, row_ptr,
                                                               csr_src, csr_eid, node_perm,
                                                               We1, h, nullptr, nullptr,
                                                               nullptr);
  else
    k_edge<128, false, false><<<N_NODES / 16, 256, 0, stream>>>(feat, ea, ea_bf, row_ptr,
                                                                csr_src, csr_eid, node_perm,
                                                                We1, h, nullptr, nullptr,
                                                                nullptr);

  // Layer 2: FI=128, FO=64, NT=288
  k_prep<128, 64><<<288, 128, 0, stream>>>(Wq2, bq2, Wk2, bk2, Wv2, bv2, We2, Ws2, bs2,
                                           Wt, bias);
  k_gemm_mfma<128, 288, false><<<GB64, 256, 0, stream>>>(h, Wt, bias, feat);
  if (use_perm)
    k_edge<64, false, true><<<N_NODES / 16, 256, 0, stream>>>(feat, ea, ea_bf, row_ptr,
                                                              csr_src, csr_eid, node_perm,
                                                              We2, h, nullptr, nullptr,
                                                              nullptr);
  else
    k_edge<64, false, false><<<N_NODES / 16, 256, 0, stream>>>(feat, ea, ea_bf, row_ptr,
                                                               csr_src, csr_eid, node_perm,
                                                               We2, h, nullptr, nullptr,
                                                               nullptr);

  // Layer 3: FI=64, FO=32, NT=160
  k_prep<64, 32><<<160, 64, 0, stream>>>(Wq3, bq3, Wk3, bk3, Wv3, bv3, We3, Ws3, bs3,
                                         Wt, bias);
  k_gemm_mfma<64, 160, false><<<GB64, 256, 0, stream>>>(h, Wt, bias, feat);
  if (use_perm)
    k_edge<32, true, true><<<N_NODES / 16, 256, 0, stream>>>(feat, ea, ea_bf, row_ptr,
                                                             csr_src, csr_eid, node_perm,
                                                             We3, nullptr, Wc, bc,
                                                             (float*)d_out);
  else
    k_edge<32, true, false><<<N_NODES / 16, 256, 0, stream>>>(feat, ea, ea_bf, row_ptr,
                                                              csr_src, csr_eid, node_perm,
                                                              We3, nullptr, Wc, bc,
                                                              (float*)d_out);
}

// Round 21
// 566.844 us; speedup vs baseline: 1.0643x; 1.0643x over previous
//
#include <hip/hip_runtime.h>
#include <math.h>

#define N_NODES 50000
#define N_EDGES 800000

typedef __bf16 bf16;
typedef __bf16 bf16x8 __attribute__((ext_vector_type(8)));
typedef float f32x4 __attribute__((ext_vector_type(4)));

__device__ __forceinline__ float bflo(unsigned r) {
  union { unsigned u; float f; } c; c.u = r << 16; return c.f;
}
__device__ __forceinline__ float bfhi(unsigned r) {
  union { unsigned u; float f; } c; c.u = r & 0xffff0000u; return c.f;
}

// packed 2xbf16 dot with f32 accumulate; HW instruction when available
__device__ __forceinline__ float dot2bf(unsigned a, unsigned b, float acc) {
#if defined(__has_builtin)
#if __has_builtin(__builtin_amdgcn_fdot2_f32_bf16)
  typedef __bf16 bf16x2 __attribute__((ext_vector_type(2)));
  union { unsigned u; bf16x2 v; } ca, cb;
  ca.u = a; cb.u = b;
  return __builtin_amdgcn_fdot2_f32_bf16(ca.v, cb.v, acc, false);
#else
  return acc + bflo(a) * bflo(b) + bfhi(a) * bfhi(b);
#endif
#else
  return acc + bflo(a) * bflo(b) + bfhi(a) * bfhi(b);
#endif
}

// async global->LDS, 16B per lane; LDS dest = wave-uniform base + lane*16
__device__ __forceinline__ void gload_lds16(const void* g, void* l) {
  __builtin_amdgcn_global_load_lds(
      (const __attribute__((address_space(1))) void*)g,
      (__attribute__((address_space(3))) void*)l, 16, 0, 0);
}

// ---------------- edge-index width detection (int64 vs int32, device-side) ----
__global__ void k_detect(const int* ei, int* flags) {
  if (threadIdx.x == 0 && blockIdx.x == 0) {
    int is64 = 1;
    for (int i = 0; i < 128; ++i) {
      if (ei[2 * i + 1] != 0) { is64 = 0; break; }
    }
    flags[0] = is64;
  }
}

__device__ __forceinline__ int load_idx(const int* ei, int e, int is64, int which) {
  size_t idx = (size_t)which * N_EDGES + (size_t)e;
  return is64 ? ei[2 * idx] : ei[idx];
}

// ---------------- CSR build ----------------

__global__ void k_zero(int* p, int n) {
  int i = blockIdx.x * blockDim.x + threadIdx.x;
  if (i < n) p[i] = 0;
}

__global__ void k_hist(const int* ei, const int* flags, int* counts) {
  int e = blockIdx.x * blockDim.x + threadIdx.x;
  int is64 = flags[0];
  if (e < N_EDGES) {
    int dst = load_idx(ei, e, is64, 1);
    if (dst >= 0 && dst < N_NODES) atomicAdd(&counts[dst], 1);
  }
}

// Multi-block scan: pass1 local scan per 1024-chunk, pass2 scan chunk sums,
// pass3 add carries.
__global__ void k_scan1(const int* counts, int* row_ptr, int* bsum) {
  __shared__ int buf[1024];
  int t = threadIdx.x;
  int i = blockIdx.x * 1024 + t;
  int v = (i < N_NODES) ? counts[i] : 0;
  buf[t] = v;
  __syncthreads();
  for (int off = 1; off < 1024; off <<= 1) {
    int x = (t >= off) ? buf[t - off] : 0;
    __syncthreads();
    buf[t] += x;
    __syncthreads();
  }
  if (i < N_NODES) row_ptr[i] = buf[t] - v;   // chunk-local exclusive
  if (t == 1023) bsum[blockIdx.x] = buf[1023];
}

__global__ void k_scan2(int* bsum, int* row_ptr) {   // 1 block, 64 threads
  constexpr int NB = (N_NODES + 1023) / 1024;        // 49
  int t = threadIdx.x;
  int v = (t < NB) ? bsum[t] : 0;
  int inc = v;
#pragma unroll
  for (int off = 1; off < 64; off <<= 1) {
    int x = __shfl_up(inc, off, 64);
    if (t >= off) inc += x;
  }
  if (t < NB) bsum[t] = inc - v;                     // exclusive chunk carry
  if (t == 63) row_ptr[N_NODES] = inc;               // grand total
}

__global__ void k_scan3(const int* bsum, int* row_ptr, int* cursor) {
  int i = blockIdx.x * 1024 + threadIdx.x;
  if (i < N_NODES) {
    int r = row_ptr[i] + bsum[blockIdx.x];
    row_ptr[i] = r;
    cursor[i] = r;
  }
}

// CSR scatter with FUSED ea permute (R17): thread e holds (e,pos); copying
// ea[e]->ea_bf[pos] here makes the 102MB ea read COALESCED (was random in
// the standalone k_eaperm) and deletes that kernel + its csr_eid re-read.
__global__ void k_scatter(const int* ei, const int* flags, int* cursor,
                          int* csr_src, int* csr_eid,
                          const float* __restrict__ ea, bf16* __restrict__ ea_bf) {
  int e = blockIdx.x * blockDim.x + threadIdx.x;
  int is64 = flags[0];
  if (e < N_EDGES) {
    int src = load_idx(ei, e, is64, 0);
    int dst = load_idx(ei, e, is64, 1);
    if (dst >= 0 && dst < N_NODES && src >= 0 && src < N_NODES) {
      int pos = atomicAdd(&cursor[dst], 1);
      if (pos >= 0 && pos < N_EDGES) {
        csr_src[pos] = src;
        csr_eid[pos] = e;
        if (ea_bf) {
          const float* se = ea + (size_t)e * 32;       // coalesced read
          bf16* de = ea_bf + (size_t)pos * 32;         // scattered 64B write
#pragma unroll
          for (int j = 0; j < 16; ++j) {
            float2 tv = *(const float2*)(se + 2 * j);
            union { bf16 b[2]; unsigned u; } cc;
            cc.b[0] = (bf16)tv.x; cc.b[1] = (bf16)tv.y;
            *(unsigned*)(de + 2 * j) = cc.u;
          }
        }
      }
    }
  }
}

// ---------------- degree sort (hierarchical counting sort, buckets 0..63) ----

#define DBLK 256
#define NDB ((N_NODES + DBLK - 1) / DBLK)   // 196

__global__ void k_dhist(const int* __restrict__ counts, int* __restrict__ btot) {
  __shared__ int lh[64];
  int t = threadIdx.x;
  if (t < 64) lh[t] = 0;
  __syncthreads();
  int n = blockIdx.x * DBLK + t;
  if (n < N_NODES) atomicAdd(&lh[min(counts[n], 63)], 1);
  __syncthreads();
  if (t < 64 && lh[t] > 0) atomicAdd(&btot[t], lh[t]);
}

__global__ void k_dbase(const int* __restrict__ btot, int* __restrict__ dcursor) {
  int t = threadIdx.x;
  int v = btot[t];
  int inc = v;
#pragma unroll
  for (int off = 1; off < 64; off <<= 1) {
    int x = __shfl_up(inc, off, 64);
    if (t >= off) inc += x;
  }
  dcursor[t] = inc - v;
}

__global__ void k_dscatter(const int* __restrict__ counts, int* __restrict__ dcursor,
                           int* __restrict__ node_perm) {
  __shared__ int lh[64];
  __shared__ int lbase[64];
  int t = threadIdx.x;
  if (t < 64) lh[t] = 0;
  __syncthreads();
  int n = blockIdx.x * DBLK + t;
  int b = 0, lrank = 0;
  bool valid = (n < N_NODES);
  if (valid) {
    b = min(counts[n], 63);
    lrank = atomicAdd(&lh[b], 1);     // LDS atomic with return: fast
  }
  __syncthreads();
  if (t < 64) {
    int c = lh[t];
    lbase[t] = (c > 0) ? atomicAdd(&dcursor[t], c) : 0;  // <=64 global atomics/block
  }
  __syncthreads();
  if (valid) node_perm[lbase[b] + lrank] = n;
}

// ---------------- weight prep: Wt[pos][k-swz] = combined^T (bf16), bias[pos] ----
// Feat-position permutation folded here (GEMM epilogue is identity).
// k index XOR-swizzled within each 8-row group (ks = k ^ ((pos&7)<<3)) so the
// GEMM stages Wt LINEARLY via global_load_lds and still gets conflict-free
// ds_read_b128 (rule #21: swizzle SOURCE + READ, keep LDS dest linear).

template <int FI, int FO>
__global__ void k_prep(const float* __restrict__ Wq, const float* __restrict__ bq,
                       const float* __restrict__ Wk, const float* __restrict__ bk,
                       const float* __restrict__ Wv, const float* __restrict__ bv,
                       const float* __restrict__ We,
                       const float* __restrict__ Ws, const float* __restrict__ bs,
                       bf16* __restrict__ Wt, float* __restrict__ bias) {
  constexpr int CPL = FO / 16;
  int n = blockIdx.x;    // 0..NT-1 (combined-column space)
  int k = threadIdx.x;   // 0..FI-1
  int pos;
  if (n < 4 * FO) {
    int sel = n / FO, c = n - sel * FO;
    if (sel == 0) pos = c;
    else if (sel == 3) pos = 3 * FO + c;
    else {
      int g = c / CPL, o = c - g * CPL;
      pos = FO + g * 2 * CPL + (sel == 2 ? CPL : 0) + o;
    }
  } else {
    pos = n;
  }
  int ks = k ^ ((pos & 7) << 3);          // bank-conflict swizzle (see above)
  if (n < 4 * FO) {
    int sel = n / FO, c = n - sel * FO;
    const float* W = sel == 0 ? Wq : sel == 1 ? Wk : sel == 2 ? Wv : Ws;
    Wt[(size_t)pos * FI + ks] = (bf16)W[(size_t)k * FO + c];
    if (k == 0) bias[pos] = (sel == 0 ? bq : sel == 1 ? bk : sel == 2 ? bv : bs)[c];
  } else {
    int j = n - 4 * FO;
    float acc = 0.f;
    for (int c = 0; c < FO; ++c) acc += Wq[(size_t)k * FO + c] * We[(size_t)j * FO + c];
    Wt[(size_t)pos * FI + ks] = (bf16)acc;
    if (k == 0) {
      float b = 0.f;
      for (int c = 0; c < FO; ++c) b += bq[c] * We[(size_t)j * FO + c];
      bias[pos] = b;
    }
  }
}

// ---------------- MFMA node GEMM -> feat (identity layout) ----------------
// R12 verified: async global_load_lds double-buffered Wt staging took the
// GEMM off the critical list. Block = 64 nodes (4 waves x 16); x frags in
// regs (read once); per chunk: prefetch next Wt tile -> 16 ds_read_b128 +
// 16 MFMA -> packed 8B stores -> barrier. Source-swizzled Wt -> conflict-free.

template <int K, int NT, bool AF32>
__global__ __launch_bounds__(256) void k_gemm_mfma(const void* __restrict__ A,
                                                   const bf16* __restrict__ Wt,
                                                   const float* __restrict__ bias,
                                                   bf16* __restrict__ feat) {
  constexpr int NKB = K / 32;
  constexpr int NCH = (NT + 63) / 64;
  constexpr int CHB = 64 * K * 2;           // full-chunk bytes (16KB @ K=128)
  __shared__ char wbuf[2 * CHB];
  int t = threadIdx.x;
  int lane = t & 63;
  int w = t >> 6;
  int half = lane & 15;
  int quad = lane >> 4;
  int m0 = blockIdx.x * 64 + w * 16;        // wave's 16-node strip
  bool act = (m0 < N_NODES);                // uniform per wave (N%16==0)

  // x fragments in regs, read ONCE (R9 property; R10 showed re-read costs)
  bf16x8 afr[NKB];
  {
    int row = act ? (m0 + half) : (N_NODES - 16 + half);
#pragma unroll
    for (int kb = 0; kb < NKB; ++kb) {
      size_t aoff = (size_t)row * K + kb * 32 + quad * 8;
      if constexpr (AF32) {
        const float* Af = (const float*)A;
        f32x4 lo = *(const f32x4*)(Af + aoff);
        f32x4 hi = *(const f32x4*)(Af + aoff + 4);
#pragma unroll
        for (int j = 0; j < 4; ++j) { afr[kb][j] = (bf16)lo[j]; afr[kb][4 + j] = (bf16)hi[j]; }
      } else {
        afr[kb] = *(const bf16x8*)((const bf16*)A + aoff);
      }
    }
  }

  // async stage of Wt chunk ch into buffer b (linear LDS; source pre-swizzled)
  auto stage = [&](int ch, int b) {
    int cols = NT - ch * 64; if (cols > 64) cols = 64;
    int nb = cols * K * 2;                          // multiple of 4096
    const char* gsrc = (const char*)Wt + (size_t)ch * 64 * K * 2;
    char* lbase = wbuf + b * CHB;
    for (int off = w * 1024; off < nb; off += 4096) // wave-uniform iteration
      gload_lds16(gsrc + off + lane * 16, lbase + off);
  };

  stage(0, 0);
  __syncthreads();                                  // drains vmcnt (guide m97)

  for (int ch = 0; ch < NCH; ++ch) {
    if (ch + 1 < NCH) stage(ch + 1, (ch + 1) & 1);  // prefetch BEFORE compute
    const char* lb = wbuf + (ch & 1) * CHB;
    int c0 = ch * 64;
    f32x4 acc[4] = {};
#pragma unroll
    for (int f = 0; f < 4; ++f) {
      int cb = c0 + f * 16;
      if (cb < NT) {
        int lc = f * 16 + half;                     // local col in chunk
#pragma unroll
        for (int kb = 0; kb < NKB; ++kb) {
          int lin = kb * 64 + quad * 16;
          int swz = lin ^ ((lc & 7) << 4);          // matches k_prep swizzle
          bf16x8 b = *(const bf16x8*)(lb + lc * (K * 2) + swz);
          acc[f] = __builtin_amdgcn_mfma_f32_16x16x32_bf16(b, afr[kb], acc[f], 0, 0, 0);
        }
      }
    }
    if (act) {
#pragma unroll
      for (int f = 0; f < 4; ++f) {
        int cb = c0 + f * 16;
        if (cb < NT) {
          int fcol = cb + quad * 4;                 // 4 consecutive features
          f32x4 bv = *(const f32x4*)(bias + fcol);
          union { bf16 b[4]; uint2 u; } pk;
#pragma unroll
          for (int r = 0; r < 4; ++r) pk.b[r] = (bf16)(acc[f][r] + bv[r]);
          *(uint2*)(feat + (size_t)(m0 + half) * NT + fcol) = pk.u;   // 8B store
        }
      }
    }
    __syncthreads();                                // next chunk staged + safe swap
  }
}

// ---------------- edge attention: one 16-LANE GROUP per dst node ----------------
// R12 version RESTORED (R13/R16 lesson: the 2-stage register pipeline cost
// 36 VGPR -> occupancy 38->20% -> HBM 42->34% -> 81->99us. TLP, not per-wave
// ILP, fills the memory duty cycle here; keep VGPR at 52.)
// 4 nodes per wave (CPL = FO/16 dims/lane); U=4 edge batching.

template <int FO, bool FINAL, bool PERM>
__global__ __launch_bounds__(256) void k_edge(const bf16* __restrict__ feat,
                                              const float* __restrict__ ea,
                                              const bf16* __restrict__ ea_bf,
                                              const int* __restrict__ row_ptr,
                                              const int* __restrict__ csr_src,
                                              const int* __restrict__ csr_eid,
                                              const int* __restrict__ node_perm,
                                              const float* __restrict__ We,
                                              bf16* __restrict__ h_out,
                                              const float* __restrict__ Wc,
                                              const float* __restrict__ bc,
                                              float* __restrict__ out) {
  constexpr int FTOT = 4 * FO + 32;
  constexpr int CPL = FO / 16;   // dims per lane within 16-lane group
  constexpr int NU = CPL / 2;    // uints holding the k (resp. v) slice
  int lane16 = threadIdx.x & 15;
  int gid = blockIdx.x * 16 + (threadIdx.x >> 4);
  // heavy nodes first (perm is ascending by degree) -> no straggler tail
  int node = node_perm[N_NODES - 1 - gid];
  int cbase = CPL * lane16;
  const bf16* fq = feat + (size_t)node * FTOT;

  unsigned qr[NU];   // q packed bf16x2
  {
    const unsigned* qp = (const unsigned*)(fq + cbase);
    if constexpr (NU == 4) { uint4 t = *(const uint4*)qp; qr[0]=t.x; qr[1]=t.y; qr[2]=t.z; qr[3]=t.w; }
    else if constexpr (NU == 2) { uint2 t = *(const uint2*)qp; qr[0]=t.x; qr[1]=t.y; }
    else { qr[0] = *qp; }
  }
  float qe0, qe1;
  { unsigned r = *(const unsigned*)(fq + 4 * FO + 2 * lane16); qe0 = bflo(r); qe1 = bfhi(r); }

  float m = -INFINITY, ssum = 0.f, wacc0 = 0.f, wacc1 = 0.f;
  float vacc[CPL];
#pragma unroll
  for (int i = 0; i < CPL; ++i) vacc[i] = 0.f;

  int start = row_ptr[node], end = row_ptr[node + 1];
  const float scaleA = 1.0f / sqrtf((float)FO);

  auto loadkv = [&](int src, unsigned* kv) {
    const unsigned* base = (const unsigned*)(feat + (size_t)src * FTOT + FO) + CPL * lane16;
    if constexpr (CPL == 8) {
      uint4 a = *(const uint4*)base; uint4 b = *(const uint4*)(base + 4);
      kv[0]=a.x; kv[1]=a.y; kv[2]=a.z; kv[3]=a.w; kv[4]=b.x; kv[5]=b.y; kv[6]=b.z; kv[7]=b.w;
    } else if constexpr (CPL == 4) {
      uint4 a = *(const uint4*)base;
      kv[0]=a.x; kv[1]=a.y; kv[2]=a.z; kv[3]=a.w;
    } else {
      uint2 a = *(const uint2*)base;
      kv[0]=a.x; kv[1]=a.y;
    }
  };

  auto loadea = [&](int p, float& e0, float& e1) {
    if constexpr (PERM) {
      unsigned r = *(const unsigned*)(ea_bf + (size_t)p * 32 + 2 * lane16);
      e0 = bflo(r); e1 = bfhi(r);
    } else {
      int eid = csr_eid[p];
      float2 t = *(const float2*)(ea + (size_t)eid * 32 + 2 * lane16);
      e0 = t.x; e1 = t.y;
    }
  };

  auto update = [&](const unsigned* kv, float e0, float e1) {
    float part = qe0 * e0 + qe1 * e1;
#pragma unroll
    for (int u = 0; u < NU; ++u) part = dot2bf(kv[u], qr[u], part);
#pragma unroll
    for (int off = 1; off < 16; off <<= 1) part += __shfl_xor(part, off, 64);
    float alpha = part * scaleA;
    float mnew = fmaxf(m, alpha);
    float sc = __expf(m - mnew);   // exp(-inf)=0 on first edge
    float w = __expf(alpha - mnew);
    ssum = ssum * sc + w;
#pragma unroll
    for (int u = 0; u < NU; ++u) {
      float a = bflo(kv[NU + u]), b = bfhi(kv[NU + u]);
      vacc[2*u]   = vacc[2*u]   * sc + w * a;
      vacc[2*u+1] = vacc[2*u+1] * sc + w * b;
    }
    wacc0 = wacc0 * sc + w * e0;
    wacc1 = wacc1 * sc + w * e1;
    m = mnew;
  };

  int p = start;
  for (; p + 4 <= end; p += 4) {
    int s[4];
#pragma unroll
    for (int u = 0; u < 4; ++u) s[u] = csr_src[p + u];
    unsigned kv[4][8];           // worst case CPL=8; smaller FO uses prefix
#pragma unroll
    for (int u = 0; u < 4; ++u) loadkv(s[u], kv[u]);
    float e0[4], e1[4];
#pragma unroll
    for (int u = 0; u < 4; ++u) loadea(p + u, e0[u], e1[u]);
#pragma unroll
    for (int u = 0; u < 4; ++u) update(kv[u], e0[u], e1[u]);
  }
  for (; p < end; ++p) {
    unsigned kv0[8];
    loadkv(csr_src[p], kv0);
    float e0, e1;
    loadea(p, e0, e1);
    update(kv0, e0, e1);
  }

  float inv = (ssum > 0.f) ? 1.0f / ssum : 0.f;
  float agg[CPL];
#pragma unroll
  for (int i = 0; i < CPL; ++i) agg[i] = vacc[i];
  // fold edge-attr contribution: agg[c] += sum_j wacc[j] * We[j][c]
#pragma unroll
  for (int jh = 0; jh < 16; ++jh) {
    float w0 = __shfl(wacc0, jh, 16);
    float w1 = __shfl(wacc1, jh, 16);
    const float* r0 = We + (size_t)(2 * jh) * FO + cbase;
    const float* r1 = We + (size_t)(2 * jh + 1) * FO + cbase;
#pragma unroll
    for (int i = 0; i < CPL; ++i) agg[i] += w0 * r0[i] + w1 * r1[i];
  }
  float hv[CPL];
#pragma unroll
  for (int i = 0; i < CPL; ++i) {
    float s = (float)fq[3 * FO + cbase + i];
    hv[i] = fmaxf(agg[i] * inv + s, 0.f);
  }
  if constexpr (!FINAL) {
    unsigned o[NU];
#pragma unroll
    for (int u = 0; u < NU; ++u) {
      union { bf16 b[2]; unsigned u32; } c;
      c.b[0] = (bf16)hv[2*u]; c.b[1] = (bf16)hv[2*u+1];
      o[u] = c.u32;
    }
    unsigned* dst = (unsigned*)(h_out + (size_t)node * FO + cbase);
    if constexpr (NU == 4) { uint4 t; t.x=o[0]; t.y=o[1]; t.z=o[2]; t.w=o[3]; *(uint4*)dst = t; }
    else if constexpr (NU == 2) { uint2 t; t.x=o[0]; t.y=o[1]; *(uint2*)dst = t; }
    else { *dst = o[0]; }
  } else {
    float part2 = 0.f;
#pragma unroll
    for (int i = 0; i < CPL; ++i) part2 += hv[i] * Wc[cbase + i];
#pragma unroll
    for (int off = 1; off < 16; off <<= 1) part2 += __shfl_xor(part2, off, 64);
    if (lane16 == 0) out[node] = part2 + bc[0];   // f32 output
  }
}

// ---------------- launch ----------------

extern "C" void kernel_launch(void* const* d_in, const int* in_sizes, int n_in,
                              void* d_out, int out_size, void* d_ws, size_t ws_size,
                              hipStream_t stream) {
  (void)in_sizes; (void)n_in; (void)out_size;
  const float* x = (const float*)d_in[0];
  const int* ei = (const int*)d_in[1];
  const float* ea = (const float*)d_in[2];
  const float *Wq1 = (const float*)d_in[3], *bq1 = (const float*)d_in[4];
  const float *Wk1 = (const float*)d_in[5], *bk1 = (const float*)d_in[6];
  const float *Wv1 = (const float*)d_in[7], *bv1 = (const float*)d_in[8];
  const float *We1 = (const float*)d_in[9];
  const float *Ws1 = (const float*)d_in[10], *bs1 = (const float*)d_in[11];
  const float *Wq2 = (const float*)d_in[12], *bq2 = (const float*)d_in[13];
  const float *Wk2 = (const float*)d_in[14], *bk2 = (const float*)d_in[15];
  const float *Wv2 = (const float*)d_in[16], *bv2 = (const float*)d_in[17];
  const float *We2 = (const float*)d_in[18];
  const float *Ws2 = (const float*)d_in[19], *bs2 = (const float*)d_in[20];
  const float *Wq3 = (const float*)d_in[21], *bq3 = (const float*)d_in[22];
  const float *Wk3 = (const float*)d_in[23], *bk3 = (const float*)d_in[24];
  const float *Wv3 = (const float*)d_in[25], *bv3 = (const float*)d_in[26];
  const float *We3 = (const float*)d_in[27];
  const float *Ws3 = (const float*)d_in[28], *bs3 = (const float*)d_in[29];
  const float *Wc = (const float*)d_in[30], *bc = (const float*)d_in[31];

  char* ws = (char*)d_ws;
  size_t off = 0;
  auto alloc = [&](size_t bytes) -> void* {
    void* p = ws + off;
    off = (off + bytes + 255) & ~(size_t)255;
    return p;
  };
  bf16* h        = (bf16*)alloc((size_t)N_NODES * 128 * 2);
  int* counts    = (int*)alloc((N_NODES + 1) * 4);
  int* row_ptr   = (int*)alloc((N_NODES + 1) * 4);
  int* cursor    = (int*)alloc((N_NODES + 1) * 4);
  int* csr_src   = (int*)alloc((size_t)N_EDGES * 4);
  int* csr_eid   = (int*)alloc((size_t)N_EDGES * 4);
  int* flags     = (int*)alloc(256);
  bf16* Wt       = (bf16*)alloc(544 * 128 * 2);
  float* bias    = (float*)alloc(544 * 4);
  bf16* feat     = (bf16*)alloc((size_t)N_NODES * 544 * 2);
  int* bsum      = (int*)alloc(64 * 4);
  int* dcount    = (int*)alloc(64 * 4);     // bucket totals
  int* dcursor   = (int*)alloc(64 * 4);     // bucket cursors (bases)
  int* node_perm = (int*)alloc((size_t)N_NODES * 4);
  bf16* ea_bf    = (bf16*)alloc((size_t)N_EDGES * 32 * 2);   // +51.2 MB
  // fall back to un-permuted path if workspace can't hold ea_bf (~126 MB total)
  bool use_perm = (ws_size == 0) || (off <= ws_size);

  constexpr int NB = (N_NODES + 1023) / 1024;   // 49 scan chunks
  constexpr int GB64 = (N_NODES + 63) / 64;     // 782 gemm blocks (64 nodes each)

  // index-width detection + CSR build (shared by all 3 layers)
  k_detect<<<1, 1, 0, stream>>>(ei, flags);
  k_zero<<<(N_NODES + 256) / 256, 256, 0, stream>>>(counts, N_NODES + 1);
  k_zero<<<1, 64, 0, stream>>>(dcount, 64);
  k_hist<<<(N_EDGES + 255) / 256, 256, 0, stream>>>(ei, flags, counts);
  k_scan1<<<NB, 1024, 0, stream>>>(counts, row_ptr, bsum);
  k_scan2<<<1, 64, 0, stream>>>(bsum, row_ptr);
  k_scan3<<<NB, 1024, 0, stream>>>(bsum, row_ptr, cursor);
  // degree sort (hierarchical: LDS hist + per-block bucket reservation)
  k_dhist<<<NDB, DBLK, 0, stream>>>(counts, dcount);
  k_dbase<<<1, 64, 0, stream>>>(dcount, dcursor);
  k_dscatter<<<NDB, DBLK, 0, stream>>>(counts, dcursor, node_perm);
  // CSR scatter with fused ea permute (coalesced ea read; replaces k_eaperm)
  k_scatter<<<(N_EDGES + 255) / 256, 256, 0, stream>>>(ei, flags, cursor, csr_src, csr_eid,
                                                       ea, use_perm ? ea_bf : nullptr);

  // Layer 1: FI=128, FO=128, NT=544
  k_prep<128, 128><<<544, 128, 0, stream>>>(Wq1, bq1, Wk1, bk1, Wv1, bv1, We1, Ws1, bs1,
                                            Wt, bias);
  k_gemm_mfma<128, 544, true><<<GB64, 256, 0, stream>>>(x, Wt, bias, feat);
  if (use_perm)
    k_edge<128, false, true><<<N_NODES / 16, 256, 0, stream>>>(feat, ea, ea_bf, row_ptr,
                                                               csr_src, csr_eid, node_perm,
                                                               We1, h, nullptr, nullptr,
                                                               nullptr);
  else
    k_edge<128, false, false><<<N_NODES / 16, 256, 0, stream>>>(feat, ea, ea_bf, row_ptr,
                                                                csr_src, csr_eid, node_perm,
                                                                We1, h, nullptr, nullptr,
                                                                nullptr);

  // Layer 2: FI=128, FO=64, NT=288
  k_prep<128, 64><<<288, 128, 0, stream>>>(Wq2, bq2, Wk2, bk2, Wv2, bv2, We2, Ws2, bs2,
                                           Wt, bias);
  k_gemm_mfma<128, 288, false><<<GB64, 256, 0, stream>>>(h, Wt, bias, feat);
  if (use_perm)
    k_edge<64, false, true><<<N_NODES / 16, 256, 0, stream>>>(feat, ea, ea_bf, row_ptr,
                                                              csr_src, csr_eid, node_perm,
                                                              We2, h, nullptr, nullptr,
                                                              nullptr);
  else
    k_edge<64, false, false><<<N_NODES / 16, 256, 0, stream>>>(feat, ea, ea_bf, row_ptr,
                                                               csr_src, csr_eid, node_perm,
                                                               We2, h, nullptr, nullptr,
                                                               nullptr);

  // Layer 3: FI=64, FO=32, NT=160
  k_prep<64, 32><<<160, 64, 0, stream>>>(Wq3, bq3, Wk3, bk3, Wv3, bv3, We3, Ws3, bs3,
                                         Wt, bias);
  k_gemm_mfma<64, 160, false><<<GB64, 256, 0, stream>>>(h, Wt, bias, feat);
  if (use_perm)
    k_edge<32, true, true><<<N_NODES / 16, 256, 0, stream>>>(feat, ea, ea_bf, row_ptr,
                                                             csr_src, csr_eid, node_perm,
                                                             We3, nullptr, Wc, bc,
                                                             (float*)d_out);
  else
    k_edge<32, true, false><<<N_NODES / 16, 256, 0, stream>>>(feat, ea, ea_bf, row_ptr,
                                                              csr_src, csr_eid, node_perm,
                                                              We3, nullptr, Wc, bc,
                                                              (float*)d_out);
}